// Round 16
// baseline (33358.658 us; speedup 1.0000x reference)
//
#include <hip/hip_runtime.h>
#include <math.h>

// GradPooling: x (32,56,56,256) f32 NHWC, pool=3 stride=2 pad=2 -> (32,29,29,256)
// gate = d_center > theta_final; theta_final = v1 = smallest d_center > theta_m8;
// theta_m8 = mod-8-chain strict f32 fold of flat dcol (bit-exact vs ref; R9-R15).
// R16: inline-asm consume loop (8-deep ds_read_b128 pipeline, counted lgkmcnt)
// inside R15's producer/consumer structure. Adds hide ds_read issue in dep-stalls.

#define NB 32
#define H 56
#define W 56
#define C 256
#define OH 29
#define OW 29
#define NTOT 62005248u
#define K_CH 7750656u       // per-chain length = NTOT/8 = 2^10 * 3^2 * 29^2
#define TP 1856             // per-chain elems per tile (divides K_CH)
#define TROW 1860           // LDS row stride floats (7440B: 16B-aligned, bank 4r)
#define NT4 4176            // K_CH / TP exactly
#define T_F4 3712           // float4s per tile = 8*TP/4
#define R_F4 464            // float4s per row = TP/4
// fallback tiling (R10-validated)
#define QT 1024
#define TILE_F (QT * 8)
#define NTILES 7569

__device__ __forceinline__ float xat(const float* __restrict__ x, int n, int r, int s, int c) {
    if ((unsigned)r < (unsigned)H && (unsigned)s < (unsigned)W)
        return x[(((size_t)n * H + r) * W + s) * C + c];
    return 0.f;
}

// dcol flat element f (C-order (9,32,256,29,29)) -> f32, elementwise = ref
__device__ __forceinline__ float dcol_val(const float* __restrict__ x, unsigned f) {
    unsigned t  = f / 6889472u;  unsigned r = f - t * 6889472u;   // 32*256*841
    unsigned n  = r / 215296u;   r -= n * 215296u;                // 256*841
    unsigned c  = r / 841u;      r -= c * 841u;
    unsigned oh = r / 29u;       unsigned ow = r - oh * 29u;
    int y  = (int)(t / 3u);
    int xx = (int)(t - 3u * (t / 3u));
    int i = y + 2 * (int)oh - 2;
    int j = xx + 2 * (int)ow - 2;
    if (i < 0 || j < 0) return 0.f;   // dp zero padding
    float a = xat(x, n, i, j, c);
    float b = xat(x, n, i - 2, j, c);
    float e = xat(x, n, i, j - 2, c);
    return 2.0f * (fabsf(a - b) + fabsf(a - e));
}

// ---- tile-row-major materialization:
// val2[((q/TP)*8 + r)*TP + q%TP] = dcol_val(8q + r)
__global__ __launch_bounds__(256) void k_dcolT2(const float* __restrict__ x,
                                                float* __restrict__ val2) {
    unsigned q = (unsigned)(blockIdx.x * 256 + threadIdx.x);
    if (q >= K_CH) return;
    const unsigned t = q / TP, c = q % TP;
#pragma unroll
    for (unsigned r = 0; r < 8; ++r) {
        val2[((size_t)t * 8u + r) * TP + c] = dcol_val(x, q * 8u + r);
    }
}

// producers copy tile t (row-major [8][R_F4] float4) into padded LDS tile
__device__ __forceinline__ void fill_tile(const float* __restrict__ val2,
                                          float* __restrict__ dst, int t, int tid) {
    const float4* src = reinterpret_cast<const float4*>(val2) + (size_t)t * T_F4;
    float4* d4 = reinterpret_cast<float4*>(dst);
    for (int i4 = tid - 64; i4 < T_F4; i4 += 448) {
        const int row = i4 / R_F4;
        const int c4  = i4 - row * R_F4;
        d4[row * (TROW / 4) + c4] = src[i4];
    }
}

// one pipeline step: oldest group ready -> 4 ordered adds -> prefetch next iter
#define GRP(G0,G1,G2,G3,OFF) \
    "s_waitcnt lgkmcnt(7)\n\t" \
    "v_add_f32 %0, %0, v" #G0 "\n\t" \
    "v_add_f32 %0, %0, v" #G1 "\n\t" \
    "v_add_f32 %0, %0, v" #G2 "\n\t" \
    "v_add_f32 %0, %0, v" #G3 "\n\t" \
    "ds_read_b128 v[" #G0 ":" #G3 "], v77 offset:" #OFF "\n\t"

// ---- producer/consumer fold, asm consumer (8-deep b128 pipeline) ----
__global__ __launch_bounds__(512) void k_fold8t(const float* __restrict__ val2,
                                                float* __restrict__ thr_m8) {
    __shared__ float buf[2][8 * TROW + 32];   // +32 floats: prefetch-overrun pad
    const int tid = threadIdx.x;

    if (tid >= 64) fill_tile(val2, buf[0], 0, tid);
    __syncthreads();

    float acc = 0.f;
    const int r = tid & 7;

    for (int t = 0; t < NT4; ++t) {
        if (tid >= 64) {
            if (t + 1 < NT4) fill_tile(val2, buf[(t + 1) & 1], t + 1, tid);
        } else {
            __builtin_amdgcn_s_setprio(1);
            unsigned lbase = (unsigned)(unsigned long long)
                ((__attribute__((address_space(3))) float*)(&buf[t & 1][r * TROW]));
            asm volatile(
                "v_mov_b32 v77, %1\n\t"
                "ds_read_b128 v[40:43], v77 offset:0\n\t"
                "ds_read_b128 v[44:47], v77 offset:16\n\t"
                "ds_read_b128 v[48:51], v77 offset:32\n\t"
                "ds_read_b128 v[52:55], v77 offset:48\n\t"
                "ds_read_b128 v[56:59], v77 offset:64\n\t"
                "ds_read_b128 v[60:63], v77 offset:80\n\t"
                "ds_read_b128 v[64:67], v77 offset:96\n\t"
                "ds_read_b128 v[68:71], v77 offset:112\n\t"
                "s_mov_b32 s20, 58\n\t"
                "1:\n\t"
                GRP(40,41,42,43,128)
                GRP(44,45,46,47,144)
                GRP(48,49,50,51,160)
                GRP(52,53,54,55,176)
                GRP(56,57,58,59,192)
                GRP(60,61,62,63,208)
                GRP(64,65,66,67,224)
                GRP(68,69,70,71,240)
                "v_add_u32 v77, 128, v77\n\t"
                "s_sub_u32 s20, s20, 1\n\t"
                "s_cmp_lg_u32 s20, 0\n\t"
                "s_cbranch_scc1 1b\n\t"
                "s_waitcnt lgkmcnt(0)\n\t"
                : "+v"(acc)
                : "v"(lbase)
                : "v40","v41","v42","v43","v44","v45","v46","v47",
                  "v48","v49","v50","v51","v52","v53","v54","v55",
                  "v56","v57","v58","v59","v60","v61","v62","v63",
                  "v64","v65","v66","v67","v68","v69","v70","v71",
                  "v77","s20","scc","memory");
            __builtin_amdgcn_s_setprio(0);
        }
        __syncthreads();
    }

    if (tid < 64) {
        // exact same horizontal association as the validated fold
        float t1 = acc + __shfl(acc, tid + 4, 64);
        float t2 = t1 + __shfl(t1, tid + 2, 64);
        float t3 = t2 + __shfl(t2, tid + 1, 64);
        if (tid == 0) thr_m8[0] = t3 / 62005248.0f;
    }
}
#undef GRP

// ---- fallback fold (R10-validated): on-the-fly producers, if ws too small ----
__global__ __launch_bounds__(1024) void k_fold8(const float* __restrict__ x,
                                                float* __restrict__ thr_m8) {
    __shared__ float buf[2][TILE_F];
    const int tid = threadIdx.x;
    if (tid >= 64) {
        for (int idx = tid - 64; idx < TILE_F; idx += 960)
            buf[0][idx] = dcol_val(x, (unsigned)idx);
    }
    __syncthreads();
    float acc = 0.f;
    const int r = tid & 7;
    for (int t = 0; t < NTILES; ++t) {
        if (tid >= 64) {
            if (t + 1 < NTILES) {
                const unsigned base = (unsigned)(t + 1) * TILE_F;
                float* nb = buf[(t + 1) & 1];
                for (int idx = tid - 64; idx < TILE_F; idx += 960)
                    nb[idx] = dcol_val(x, base + (unsigned)idx);
            }
        } else {
            const float* bp = buf[t & 1];
#pragma unroll 16
            for (int qq = 0; qq < QT; ++qq)
                acc += bp[8 * qq + r];
        }
        __syncthreads();
    }
    if (tid < 64) {
        float t1 = acc + __shfl(acc, tid + 4, 64);
        float t2 = t1 + __shfl(t1, tid + 2, 64);
        float t3 = t2 + __shfl(t2, tid + 1, 64);
        if (tid == 0) thr_m8[0] = t3 / 62005248.0f;
    }
}

__global__ void k_cinit(unsigned* cand) { cand[0] = 0x7F800000u; }  // +inf

// smallest d_center strictly above thr_m8 (uint atomicMin == float min for d>=0)
__global__ __launch_bounds__(256) void k_cand(const float* __restrict__ x,
                                              const float* __restrict__ thr_m8,
                                              unsigned* __restrict__ cand) {
    const float thr = thr_m8[0];
    const int bid = blockIdx.x;           // (n*OH + oh)*OW + ow
    const int ow = bid % OW;
    const int oh = (bid / OW) % OH;
    const int n = bid / (OW * OH);
    if (oh == 0 || ow == 0) return;
    const int c = threadIdx.x;
    const int r = 2 * oh - 1, s = 2 * ow - 1;
    float a = xat(x, n, r, s, c);
    float b = xat(x, n, r - 2, s, c);
    float e = xat(x, n, r, s - 2, c);
    float d = 2.0f * (fabsf(a - b) + fabsf(a - e));
    if (d > thr) atomicMin(cand, __float_as_uint(d));
}

__global__ void k_sel(const float* __restrict__ thr_m8,
                      const unsigned* __restrict__ cand,
                      float* __restrict__ thrf) {
    float v = __uint_as_float(cand[0]);
    thrf[0] = isinf(v) ? thr_m8[0] : v;   // theta = v1 (gate is strict >)
}

__device__ __forceinline__ float4 ldx(const float* __restrict__ xb, int r, int s, int c) {
    if ((unsigned)r < (unsigned)H && (unsigned)s < (unsigned)W) {
        return *reinterpret_cast<const float4*>(xb + ((size_t)(r * W + s)) * C + c);
    }
    return make_float4(0.f, 0.f, 0.f, 0.f);
}

__device__ __forceinline__ float getl(const float4& v, int l) {
    return l == 0 ? v.x : (l == 1 ? v.y : (l == 2 ? v.z : v.w));
}

__global__ __launch_bounds__(256) void k_pool(const float* __restrict__ x,
                                              const float* __restrict__ thrf,
                                              float* __restrict__ out) {
    const float thresh = thrf[0];
    const int bid = blockIdx.x;            // ((n*OH)+oh)*8 + owg
    const int owg = bid & 7;
    const int oh = (bid >> 3) % OH;
    const int n = (bid >> 3) / OH;
    const int t = threadIdx.x;
    const int cq = (t & 63) << 2;
    const int ow = (owg << 2) + (t >> 6);
    if (ow >= OW) return;
    const float* xb = x + (size_t)n * (H * W * C);
    const int r0 = 2 * oh - 2, s0 = 2 * ow - 2;

    float4 v[3][3];
#pragma unroll
    for (int yy = 0; yy < 3; ++yy)
#pragma unroll
        for (int xx = 0; xx < 3; ++xx)
            v[yy][xx] = ldx(xb, r0 + yy, s0 + xx, cq);

    float4 b4 = ldx(xb, r0 - 1, s0 + 1, cq);
    float4 e4 = ldx(xb, r0 + 1, s0 - 1, cq);
    float4 a4 = v[1][1];
    const bool cen_ok = (oh >= 1) && (ow >= 1);

    float outv[4];
#pragma unroll
    for (int l = 0; l < 4; ++l) {
        float m = -INFINITY, s = 0.f;
#pragma unroll
        for (int yy = 0; yy < 3; ++yy)
#pragma unroll
            for (int xx = 0; xx < 3; ++xx) {
                float q = getl(v[yy][xx], l);
                m = fmaxf(m, q);
                s += q;
            }
        float mean = s / 9.0f;
        float cen = 0.f;
        if (cen_ok) {
            float a = getl(a4, l), b = getl(b4, l), e = getl(e4, l);
            cen = 2.0f * (fabsf(a - b) + fabsf(a - e));
        }
        outv[l] = (cen > thresh) ? m : mean;
    }
    float4 o = make_float4(outv[0], outv[1], outv[2], outv[3]);
    *reinterpret_cast<float4*>(out + ((size_t)((n * OH + oh) * OW + ow)) * C + cq) = o;
}

extern "C" void kernel_launch(void* const* d_in, const int* in_sizes, int n_in,
                              void* d_out, int out_size, void* d_ws, size_t ws_size,
                              hipStream_t stream) {
    const float* x = (const float*)d_in[0];
    float* out = (float*)d_out;
    float* thr_m8 = (float*)d_ws;              // [0]
    unsigned* cand = (unsigned*)d_ws + 1;      // [1]
    float* thrf = (float*)d_ws + 2;            // [2]
    float* val2 = (float*)d_ws + 16;           // 64B-aligned tile-row-major array
    const size_t need = (16ull + NTOT) * sizeof(float);

    if (ws_size >= need) {
        k_dcolT2<<<(K_CH + 255) / 256, 256, 0, stream>>>(x, val2);
        k_fold8t<<<1, 512, 0, stream>>>(val2, thr_m8);
    } else {
        k_fold8<<<1, 1024, 0, stream>>>(x, thr_m8);
    }
    k_cinit<<<1, 1, 0, stream>>>(cand);
    k_cand<<<NB * OH * OW, 256, 0, stream>>>(x, thr_m8, cand);
    k_sel<<<1, 1, 0, stream>>>(thr_m8, cand, thrf);
    k_pool<<<NB * OH * 8, 256, 0, stream>>>(x, thrf, out);
}

// Round 17
// 32844.080 us; speedup vs baseline: 1.0157x; 1.0157x over previous
//
#include <hip/hip_runtime.h>
#include <math.h>

// GradPooling: x (32,56,56,256) f32 NHWC, pool=3 stride=2 pad=2 -> (32,29,29,256)
// gate = d_center > theta_final; theta_final = v1 = smallest d_center > theta_m8;
// theta_m8 = mod-8-chain strict f32 fold of flat dcol (bit-exact vs ref; R9-R16).
// R17: pipelined producers (9 independent loads -> fence -> 9 LDS writes) so
// producer latency overlaps the consumer dep-add chain. Consumer asm unchanged.

#define NB 32
#define H 56
#define W 56
#define C 256
#define OH 29
#define OW 29
#define NTOT 62005248u
#define K_CH 7750656u       // per-chain length = NTOT/8 = 2^10 * 3^2 * 29^2
#define TP 1856             // per-chain elems per tile (divides K_CH)
#define TROW 1860           // LDS row stride floats (7440B: 16B-aligned, bank 4r)
#define NT4 4176            // K_CH / TP exactly
#define T_F4 3712           // float4s per tile = 8*TP/4
#define R_F4 464            // float4s per row = TP/4
// fallback tiling (R10-validated)
#define QT 1024
#define TILE_F (QT * 8)
#define NTILES 7569

__device__ __forceinline__ float xat(const float* __restrict__ x, int n, int r, int s, int c) {
    if ((unsigned)r < (unsigned)H && (unsigned)s < (unsigned)W)
        return x[(((size_t)n * H + r) * W + s) * C + c];
    return 0.f;
}

// dcol flat element f (C-order (9,32,256,29,29)) -> f32, elementwise = ref
__device__ __forceinline__ float dcol_val(const float* __restrict__ x, unsigned f) {
    unsigned t  = f / 6889472u;  unsigned r = f - t * 6889472u;   // 32*256*841
    unsigned n  = r / 215296u;   r -= n * 215296u;                // 256*841
    unsigned c  = r / 841u;      r -= c * 841u;
    unsigned oh = r / 29u;       unsigned ow = r - oh * 29u;
    int y  = (int)(t / 3u);
    int xx = (int)(t - 3u * (t / 3u));
    int i = y + 2 * (int)oh - 2;
    int j = xx + 2 * (int)ow - 2;
    if (i < 0 || j < 0) return 0.f;   // dp zero padding
    float a = xat(x, n, i, j, c);
    float b = xat(x, n, i - 2, j, c);
    float e = xat(x, n, i, j - 2, c);
    return 2.0f * (fabsf(a - b) + fabsf(a - e));
}

// ---- tile-row-major materialization:
// val2[((q/TP)*8 + r)*TP + q%TP] = dcol_val(8q + r)
__global__ __launch_bounds__(256) void k_dcolT2(const float* __restrict__ x,
                                                float* __restrict__ val2) {
    unsigned q = (unsigned)(blockIdx.x * 256 + threadIdx.x);
    if (q >= K_CH) return;
    const unsigned t = q / TP, c = q % TP;
#pragma unroll
    for (unsigned r = 0; r < 8; ++r) {
        val2[((size_t)t * 8u + r) * TP + c] = dcol_val(x, q * 8u + r);
    }
}

// padded LDS float4-index for tile-linear float4-index i4
__device__ __forceinline__ int pidx(int i4) {
    const int row = i4 / R_F4;
    return row * (TROW / 4) + (i4 - row * R_F4);
}

// pipelined producer copy: 9 independent global loads -> fence -> 9 LDS writes
__device__ __forceinline__ void fill_tile(const float* __restrict__ val2,
                                          float* __restrict__ dst, int t, int tid) {
    const float4* src = reinterpret_cast<const float4*>(val2) + (size_t)t * T_F4;
    float4* d4 = reinterpret_cast<float4*>(dst);
    const int p = tid - 64;                 // 0..447
    const bool has9 = p < (T_F4 - 8 * 448); // first 128 threads take a 9th chunk
    float4 v0, v1, v2, v3, v4, v5, v6, v7, v8;
    v0 = src[p + 0 * 448];
    v1 = src[p + 1 * 448];
    v2 = src[p + 2 * 448];
    v3 = src[p + 3 * 448];
    v4 = src[p + 4 * 448];
    v5 = src[p + 5 * 448];
    v6 = src[p + 6 * 448];
    v7 = src[p + 7 * 448];
    if (has9) v8 = src[p + 8 * 448];
    __builtin_amdgcn_sched_barrier(0);      // keep all loads issued before writes
    d4[pidx(p + 0 * 448)] = v0;
    d4[pidx(p + 1 * 448)] = v1;
    d4[pidx(p + 2 * 448)] = v2;
    d4[pidx(p + 3 * 448)] = v3;
    d4[pidx(p + 4 * 448)] = v4;
    d4[pidx(p + 5 * 448)] = v5;
    d4[pidx(p + 6 * 448)] = v6;
    d4[pidx(p + 7 * 448)] = v7;
    if (has9) d4[pidx(p + 8 * 448)] = v8;
}

// one pipeline step: oldest group ready -> 4 ordered adds -> prefetch next iter
#define GRP(G0,G1,G2,G3,OFF) \
    "s_waitcnt lgkmcnt(7)\n\t" \
    "v_add_f32 %0, %0, v" #G0 "\n\t" \
    "v_add_f32 %0, %0, v" #G1 "\n\t" \
    "v_add_f32 %0, %0, v" #G2 "\n\t" \
    "v_add_f32 %0, %0, v" #G3 "\n\t" \
    "ds_read_b128 v[" #G0 ":" #G3 "], v77 offset:" #OFF "\n\t"

// ---- producer/consumer fold, asm consumer (8-deep b128 pipeline) ----
__global__ __launch_bounds__(512) void k_fold8t(const float* __restrict__ val2,
                                                float* __restrict__ thr_m8) {
    __shared__ float buf[2][8 * TROW + 32];   // +32 floats: prefetch-overrun pad
    const int tid = threadIdx.x;

    if (tid >= 64) fill_tile(val2, buf[0], 0, tid);
    __syncthreads();

    float acc = 0.f;
    const int r = tid & 7;

    for (int t = 0; t < NT4; ++t) {
        if (tid >= 64) {
            if (t + 1 < NT4) fill_tile(val2, buf[(t + 1) & 1], t + 1, tid);
        } else {
            __builtin_amdgcn_s_setprio(1);
            unsigned lbase = (unsigned)(unsigned long long)
                ((__attribute__((address_space(3))) float*)(&buf[t & 1][r * TROW]));
            asm volatile(
                "v_mov_b32 v77, %1\n\t"
                "ds_read_b128 v[40:43], v77 offset:0\n\t"
                "ds_read_b128 v[44:47], v77 offset:16\n\t"
                "ds_read_b128 v[48:51], v77 offset:32\n\t"
                "ds_read_b128 v[52:55], v77 offset:48\n\t"
                "ds_read_b128 v[56:59], v77 offset:64\n\t"
                "ds_read_b128 v[60:63], v77 offset:80\n\t"
                "ds_read_b128 v[64:67], v77 offset:96\n\t"
                "ds_read_b128 v[68:71], v77 offset:112\n\t"
                "s_mov_b32 s20, 58\n\t"
                "1:\n\t"
                GRP(40,41,42,43,128)
                GRP(44,45,46,47,144)
                GRP(48,49,50,51,160)
                GRP(52,53,54,55,176)
                GRP(56,57,58,59,192)
                GRP(60,61,62,63,208)
                GRP(64,65,66,67,224)
                GRP(68,69,70,71,240)
                "v_add_u32 v77, 128, v77\n\t"
                "s_sub_u32 s20, s20, 1\n\t"
                "s_cmp_lg_u32 s20, 0\n\t"
                "s_cbranch_scc1 1b\n\t"
                "s_waitcnt lgkmcnt(0)\n\t"
                : "+v"(acc)
                : "v"(lbase)
                : "v40","v41","v42","v43","v44","v45","v46","v47",
                  "v48","v49","v50","v51","v52","v53","v54","v55",
                  "v56","v57","v58","v59","v60","v61","v62","v63",
                  "v64","v65","v66","v67","v68","v69","v70","v71",
                  "v77","s20","scc","memory");
            __builtin_amdgcn_s_setprio(0);
        }
        __syncthreads();
    }

    if (tid < 64) {
        // exact same horizontal association as the validated fold
        float t1 = acc + __shfl(acc, tid + 4, 64);
        float t2 = t1 + __shfl(t1, tid + 2, 64);
        float t3 = t2 + __shfl(t2, tid + 1, 64);
        if (tid == 0) thr_m8[0] = t3 / 62005248.0f;
    }
}
#undef GRP

// ---- fallback fold (R10-validated): on-the-fly producers, if ws too small ----
__global__ __launch_bounds__(1024) void k_fold8(const float* __restrict__ x,
                                                float* __restrict__ thr_m8) {
    __shared__ float buf[2][TILE_F];
    const int tid = threadIdx.x;
    if (tid >= 64) {
        for (int idx = tid - 64; idx < TILE_F; idx += 960)
            buf[0][idx] = dcol_val(x, (unsigned)idx);
    }
    __syncthreads();
    float acc = 0.f;
    const int r = tid & 7;
    for (int t = 0; t < NTILES; ++t) {
        if (tid >= 64) {
            if (t + 1 < NTILES) {
                const unsigned base = (unsigned)(t + 1) * TILE_F;
                float* nb = buf[(t + 1) & 1];
                for (int idx = tid - 64; idx < TILE_F; idx += 960)
                    nb[idx] = dcol_val(x, base + (unsigned)idx);
            }
        } else {
            const float* bp = buf[t & 1];
#pragma unroll 16
            for (int qq = 0; qq < QT; ++qq)
                acc += bp[8 * qq + r];
        }
        __syncthreads();
    }
    if (tid < 64) {
        float t1 = acc + __shfl(acc, tid + 4, 64);
        float t2 = t1 + __shfl(t1, tid + 2, 64);
        float t3 = t2 + __shfl(t2, tid + 1, 64);
        if (tid == 0) thr_m8[0] = t3 / 62005248.0f;
    }
}

__global__ void k_cinit(unsigned* cand) { cand[0] = 0x7F800000u; }  // +inf

// smallest d_center strictly above thr_m8 (uint atomicMin == float min for d>=0)
__global__ __launch_bounds__(256) void k_cand(const float* __restrict__ x,
                                              const float* __restrict__ thr_m8,
                                              unsigned* __restrict__ cand) {
    const float thr = thr_m8[0];
    const int bid = blockIdx.x;           // (n*OH + oh)*OW + ow
    const int ow = bid % OW;
    const int oh = (bid / OW) % OH;
    const int n = bid / (OW * OH);
    if (oh == 0 || ow == 0) return;
    const int c = threadIdx.x;
    const int r = 2 * oh - 1, s = 2 * ow - 1;
    float a = xat(x, n, r, s, c);
    float b = xat(x, n, r - 2, s, c);
    float e = xat(x, n, r, s - 2, c);
    float d = 2.0f * (fabsf(a - b) + fabsf(a - e));
    if (d > thr) atomicMin(cand, __float_as_uint(d));
}

__global__ void k_sel(const float* __restrict__ thr_m8,
                      const unsigned* __restrict__ cand,
                      float* __restrict__ thrf) {
    float v = __uint_as_float(cand[0]);
    thrf[0] = isinf(v) ? thr_m8[0] : v;   // theta = v1 (gate is strict >)
}

__device__ __forceinline__ float4 ldx(const float* __restrict__ xb, int r, int s, int c) {
    if ((unsigned)r < (unsigned)H && (unsigned)s < (unsigned)W) {
        return *reinterpret_cast<const float4*>(xb + ((size_t)(r * W + s)) * C + c);
    }
    return make_float4(0.f, 0.f, 0.f, 0.f);
}

__device__ __forceinline__ float getl(const float4& v, int l) {
    return l == 0 ? v.x : (l == 1 ? v.y : (l == 2 ? v.z : v.w));
}

__global__ __launch_bounds__(256) void k_pool(const float* __restrict__ x,
                                              const float* __restrict__ thrf,
                                              float* __restrict__ out) {
    const float thresh = thrf[0];
    const int bid = blockIdx.x;            // ((n*OH)+oh)*8 + owg
    const int owg = bid & 7;
    const int oh = (bid >> 3) % OH;
    const int n = (bid >> 3) / OH;
    const int t = threadIdx.x;
    const int cq = (t & 63) << 2;
    const int ow = (owg << 2) + (t >> 6);
    if (ow >= OW) return;
    const float* xb = x + (size_t)n * (H * W * C);
    const int r0 = 2 * oh - 2, s0 = 2 * ow - 2;

    float4 v[3][3];
#pragma unroll
    for (int yy = 0; yy < 3; ++yy)
#pragma unroll
        for (int xx = 0; xx < 3; ++xx)
            v[yy][xx] = ldx(xb, r0 + yy, s0 + xx, cq);

    float4 b4 = ldx(xb, r0 - 1, s0 + 1, cq);
    float4 e4 = ldx(xb, r0 + 1, s0 - 1, cq);
    float4 a4 = v[1][1];
    const bool cen_ok = (oh >= 1) && (ow >= 1);

    float outv[4];
#pragma unroll
    for (int l = 0; l < 4; ++l) {
        float m = -INFINITY, s = 0.f;
#pragma unroll
        for (int yy = 0; yy < 3; ++yy)
#pragma unroll
            for (int xx = 0; xx < 3; ++xx) {
                float q = getl(v[yy][xx], l);
                m = fmaxf(m, q);
                s += q;
            }
        float mean = s / 9.0f;
        float cen = 0.f;
        if (cen_ok) {
            float a = getl(a4, l), b = getl(b4, l), e = getl(e4, l);
            cen = 2.0f * (fabsf(a - b) + fabsf(a - e));
        }
        outv[l] = (cen > thresh) ? m : mean;
    }
    float4 o = make_float4(outv[0], outv[1], outv[2], outv[3]);
    *reinterpret_cast<float4*>(out + ((size_t)((n * OH + oh) * OW + ow)) * C + cq) = o;
}

extern "C" void kernel_launch(void* const* d_in, const int* in_sizes, int n_in,
                              void* d_out, int out_size, void* d_ws, size_t ws_size,
                              hipStream_t stream) {
    const float* x = (const float*)d_in[0];
    float* out = (float*)d_out;
    float* thr_m8 = (float*)d_ws;              // [0]
    unsigned* cand = (unsigned*)d_ws + 1;      // [1]
    float* thrf = (float*)d_ws + 2;            // [2]
    float* val2 = (float*)d_ws + 16;           // 64B-aligned tile-row-major array
    const size_t need = (16ull + NTOT) * sizeof(float);

    if (ws_size >= need) {
        k_dcolT2<<<(K_CH + 255) / 256, 256, 0, stream>>>(x, val2);
        k_fold8t<<<1, 512, 0, stream>>>(val2, thr_m8);
    } else {
        k_fold8<<<1, 1024, 0, stream>>>(x, thr_m8);
    }
    k_cinit<<<1, 1, 0, stream>>>(cand);
    k_cand<<<NB * OH * OW, 256, 0, stream>>>(x, thr_m8, cand);
    k_sel<<<1, 1, 0, stream>>>(thr_m8, cand, thrf);
    k_pool<<<NB * OH * 8, 256, 0, stream>>>(x, thrf, out);
}